// Round 1
// baseline (230.166 us; speedup 1.0000x reference)
//
#include <hip/hip_runtime.h>

typedef _Float16 h4 __attribute__((ext_vector_type(4)));
typedef float    f4 __attribute__((ext_vector_type(4)));

#define N_B   128
#define N_IN  1152
#define ICH   12          // i-tiles per block
#define NCH   96          // N_IN / ICH
#define BSPL  8           // b splits
#define BCH   16          // b per block
#define TPW   3           // tiles per wave (4 waves)

// workspace layout (bytes)
#define WSWZ_SZ  (N_IN * 64 * 32 * 4)   // 9,437,184 : per-lane W fragments, fp32
#define VSUM_OFF (WSWZ_SZ)
#define VSUM_SZ  (N_B * 256 * 4)        // 131,072
#define SBUF_OFF (VSUM_OFF + VSUM_SZ)
#define SBUF_SZ  (N_B * 256 * 4)

// ---------------------------------------------------------------------------
// Setup: Wswz[i][lane][32] = W[i, o=lane&15, j=(lane>>4)*4 + t, k]  (t*8+k idx)
// Also zero Vsum and the s accumulator.
// ---------------------------------------------------------------------------
__global__ __launch_bounds__(256) void k_setup(const float* __restrict__ W,
                                               float* __restrict__ Wswz,
                                               float* __restrict__ Vsum,
                                               float* __restrict__ S) {
    int t = blockIdx.x * 256 + threadIdx.x;   // grid 288*256 = 73728 = 1152*64
    if (t < N_B * 256) { Vsum[t] = 0.f; S[t] = 0.f; }
    int i = t >> 6, lane = t & 63;
    if (i < N_IN) {
        int o = lane & 15, jq = lane >> 4;
        const f4* src = (const f4*)(W + ((size_t)((i * 16 + o) * 16 + jq * 4) * 8));
        f4* dst = (f4*)(Wswz + (size_t)t * 32);
#pragma unroll
        for (int q = 0; q < 8; q++) dst[q] = src[q];
    }
}

// ---------------------------------------------------------------------------
// Routing pass: for each (b,i) tile recompute u_hat (fp32), logits via
// split-f16 MFMA against Vsum, softmax over 'o', accumulate s.
// grid = NCH*BSPL = 768 blocks, 256 threads (4 waves, 3 tiles each).
// ---------------------------------------------------------------------------
__global__ __launch_bounds__(256, 3) void k_route(const float* __restrict__ x,
                                                  const float* __restrict__ Wswz,
                                                  const float* __restrict__ Vsum,
                                                  float* __restrict__ S,
                                                  int iter) {
    __shared__ _Float16 vsh[BCH][16][20];   // hi f16 of Vsum rows (padded)
    __shared__ _Float16 vsl[BCH][16][20];   // lo f16
    __shared__ float red[4][256];

    const int bx   = blockIdx.x;
    const int c    = bx >> 3;        // i-chunk 0..95
    const int spl  = bx & 7;
    const int i0   = c * ICH;
    const int b0   = spl * BCH;
    const int tid  = threadIdx.x;
    const int w    = tid >> 6;
    const int lane = tid & 63;
    const int lo16 = lane & 15;
    const int jq   = lane >> 4;

    // --- W fragments into registers (96 VGPR) ---
    f4 wreg[TPW][8];
    {
        const f4* wp = (const f4*)Wswz + ((size_t)(i0 + w * TPW) * 64 + lane) * 8;
#pragma unroll
        for (int t3 = 0; t3 < TPW; t3++)
#pragma unroll
            for (int q = 0; q < 8; q++) wreg[t3][q] = wp[t3 * 512 + q];
    }

    // --- Vsum staging, hi/lo split ---
    if (iter) {
#pragma unroll
        for (int e = 0; e < BCH; e++) {
            float v = Vsum[(size_t)(b0 + e) * 256 + tid];
            _Float16 h = (_Float16)v;
            _Float16 l = (_Float16)(v - (float)h);
            vsh[e][tid >> 4][tid & 15] = h;
            vsl[e][tid >> 4][tid & 15] = l;
        }
    }
    __syncthreads();

    // identity B-fragment (for U -> D-layout transpose MFMA)
    h4 idf;
#pragma unroll
    for (int t = 0; t < 4; t++) idf[t] = (_Float16)((jq * 4 + t == lo16) ? 1.0f : 0.0f);

    for (int bb = 0; bb < BCH; bb++) {
        const int b = b0 + bb;
        float sacc[4] = {0.f, 0.f, 0.f, 0.f};
        h4 bh, bl;
        if (iter) {
#pragma unroll
            for (int t = 0; t < 4; t++) {
                bh[t] = vsh[bb][lo16][jq * 4 + t];
                bl[t] = vsl[bb][lo16][jq * 4 + t];
            }
        }
#pragma unroll
        for (int t3 = 0; t3 < TPW; t3++) {
            const int i = i0 + w * TPW + t3;
            const float* xp = x + ((size_t)b * N_IN + i) * 8;
            f4 xa = *((const f4*)xp);
            f4 xb = *((const f4*)xp + 1);
            float u[4];
#pragma unroll
            for (int t = 0; t < 4; t++) {
                float a = 0.f;
#pragma unroll
                for (int k = 0; k < 4; k++) a = fmaf(wreg[t3][2 * t][k], xa[k], a);
#pragma unroll
                for (int k = 0; k < 4; k++) a = fmaf(wreg[t3][2 * t + 1][k], xb[k], a);
                u[t] = a;
            }
            if (iter == 0) {
                // uniform c = 1/16, accumulate at A-layout positions
#pragma unroll
                for (int t = 0; t < 4; t++) sacc[t] = fmaf(u[t], 0.0625f, sacc[t]);
            } else {
                h4 uh, ul;
#pragma unroll
                for (int t = 0; t < 4; t++) {
                    _Float16 h = (_Float16)u[t];
                    uh[t] = h;
                    ul[t] = (_Float16)(u[t] - (float)h);
                }
                f4 z = {0.f, 0.f, 0.f, 0.f};
                // logits L = U @ Vsum^T, split f16 for ~fp32 accuracy
                f4 L = __builtin_amdgcn_mfma_f32_16x16x16f16(uh, bh, z, 0, 0, 0);
                L = __builtin_amdgcn_mfma_f32_16x16x16f16(ul, bh, L, 0, 0, 0);
                L = __builtin_amdgcn_mfma_f32_16x16x16f16(uh, bl, L, 0, 0, 0);
                // U in D-layout via identity B
                f4 ud = __builtin_amdgcn_mfma_f32_16x16x16f16(uh, idf, z, 0, 0, 0);
                ud = __builtin_amdgcn_mfma_f32_16x16x16f16(ul, idf, ud, 0, 0, 0);
                // softmax over o (rows of column lo16); |L| <~ 45 so no max-sub needed
                float p[4]; float zs = 0.f;
#pragma unroll
                for (int t = 0; t < 4; t++) { p[t] = __expf(L[t]); zs += p[t]; }
                zs += __shfl_xor(zs, 16);
                zs += __shfl_xor(zs, 32);
                float rin = __builtin_amdgcn_rcpf(zs);
#pragma unroll
                for (int t = 0; t < 4; t++) sacc[t] = fmaf(p[t] * rin, ud[t], sacc[t]);
            }
        }
        // block reduction over the 4 waves, then one atomicAdd per od element
        if (iter == 0) {
#pragma unroll
            for (int t = 0; t < 4; t++) red[w][lo16 * 16 + jq * 4 + t] = sacc[t];
        } else {
#pragma unroll
            for (int t = 0; t < 4; t++) red[w][(jq * 4 + t) * 16 + lo16] = sacc[t];
        }
        __syncthreads();
        float val = (red[0][tid] + red[1][tid]) + (red[2][tid] + red[3][tid]);
        atomicAdd(S + (size_t)b * 256 + tid, val);
        __syncthreads();
    }
}

// ---------------------------------------------------------------------------
// Squash: v = squash(s); out = v; Vsum += v; s = 0 (for next pass).
// grid = 128 blocks (one per b), 256 threads (od).
// ---------------------------------------------------------------------------
__global__ __launch_bounds__(256) void k_squash(float* __restrict__ S,
                                                float* __restrict__ Vsum,
                                                float* __restrict__ out) {
    int b = blockIdx.x, tid = threadIdx.x;
    size_t idx = (size_t)b * 256 + tid;
    float s = S[idx];
    S[idx] = 0.f;
    float sq = s * s;
    sq += __shfl_xor(sq, 1);
    sq += __shfl_xor(sq, 2);
    sq += __shfl_xor(sq, 4);
    sq += __shfl_xor(sq, 8);
    float scale = sq * __builtin_amdgcn_rcpf(1.f + sq);
    float rs = __builtin_amdgcn_rsqf(sq + 1e-8f);
    float v = s * scale * rs;
    out[idx] = v;
    Vsum[idx] += v;
}

// ---------------------------------------------------------------------------
extern "C" void kernel_launch(void* const* d_in, const int* in_sizes, int n_in,
                              void* d_out, int out_size, void* d_ws, size_t ws_size,
                              hipStream_t stream) {
    (void)in_sizes; (void)n_in; (void)out_size; (void)ws_size;
    const float* x = (const float*)d_in[0];
    const float* W = (const float*)d_in[1];
    float* out  = (float*)d_out;
    char*  ws   = (char*)d_ws;
    float* Wswz = (float*)ws;
    float* Vsum = (float*)(ws + VSUM_OFF);
    float* S    = (float*)(ws + SBUF_OFF);

    k_setup<<<288, 256, 0, stream>>>(W, Wswz, Vsum, S);
    for (int it = 0; it < 3; it++) {
        k_route<<<NCH * BSPL, 256, 0, stream>>>(x, Wswz, Vsum, S, it);
        k_squash<<<N_B, 256, 0, stream>>>(S, Vsum, out);
    }
}